// Round 20
// baseline (35.260 us; speedup 1.0000x reference)
//
#include <hip/hip_runtime.h>

#define NPTS 4096
#define N0V  10242
#define EPSV 1e-5f
#define SLOTS 16
#define FXS 16777216.0   // 2^24 fixed-point scale

typedef unsigned short ushortT;
typedef unsigned long long ullT;
typedef __attribute__((ext_vector_type(8))) short short8;
typedef __attribute__((ext_vector_type(4))) float f32x4;

__device__ __forceinline__ float fmul(float a,float b){return __fmul_rn(a,b);}
__device__ __forceinline__ float fadd(float a,float b){return __fadd_rn(a,b);}
__device__ __forceinline__ float fsub(float a,float b){return __fsub_rn(a,b);}

__device__ __forceinline__ ushortT f2bf(float x){
  unsigned u = __float_as_uint(x);
  u = (u + 0x7fffu + ((u>>16)&1u)) >> 16;
  return (ushortT)u;
}
__device__ __forceinline__ float bf2f(ushortT u){
  return __uint_as_float(((unsigned)u) << 16);
}

// ---- per-wave 16x16 MFMA tile ----
template<int NS>
__device__ __forceinline__ void tile_mm(const ushortT* xa, const ushortT* wt, int wstr,
    int li, int hi, int rt, int colg, f32x4& acc)
{
  acc = (f32x4){0.f,0.f,0.f,0.f};
  const ushortT* wbp = wt + colg*wstr + hi*8;
  const ushortT* xap = xa + (rt*16 + li)*168 + hi*8;
  #pragma unroll
  for (int s=0;s<NS;s++){
    short8 bb = *(const short8*)(wbp + s*32);
    short8 a0 = *(const short8*)(xap + s*32);
    acc = __builtin_amdgcn_mfma_f32_16x16x32_bf16(a0, bb, acc, 0,0,0);
  }
}

// ---- per-wave partials -> DETERMINISTIC fixed-point int64 atomicAdd into 16 slots ----
// (float atomicAdd ordering is run-to-run nondeterministic -> failed graph-replay check R19;
//  integer adds are associative/commutative -> bitwise-reproducible stats)
__device__ __forceinline__ void tile_partials(const f32x4& acc, ullT* __restrict__ slotL,
                                              int blk, int lane, int colg)
{
  float s1=0.f, s2=0.f;
  #pragma unroll
  for (int r=0;r<4;r++){ s1 += acc[r]; s2 = fmaf(acc[r],acc[r],s2); }
  s1 += __shfl_xor(s1,16); s1 += __shfl_xor(s1,32);
  s2 += __shfl_xor(s2,16); s2 += __shfl_xor(s2,32);
  if (lane < 16){
    ullT* sl = slotL + (blk & (SLOTS-1))*256;
    long long q1 = __double2ll_rn((double)s1 * FXS);
    long long q2 = __double2ll_rn((double)s2 * FXS);
    atomicAdd(&sl[colg],       (ullT)q1);
    atomicAdd(&sl[128 + colg], (ullT)q2);
  }
}

// ---- stats from previous kernel's slots: plain int64 loads (inter-dispatch barrier = sync) ----
__device__ __forceinline__ void slot_stats(const ullT* __restrict__ slotL,
    const float* __restrict__ g, const float* __restrict__ be,
    float* red2, float* stS, float* stB, int t)
{
  if (t < 256){
    long long v = 0;
    #pragma unroll
    for (int s=0;s<SLOTS;s++) v += (long long)slotL[s*256 + t];
    red2[t] = (float)((double)v * (1.0/FXS));
  }
  __syncthreads();
  if (t < 128){
    float S = red2[t], Q = red2[128 + t];
    float mean = S * (1.0f/8192.0f);
    float var  = Q * (1.0f/8192.0f) - mean*mean;
    float inv  = 1.0f / __fsqrt_rn(var + EPSV);
    float sc = g[t]*inv;
    stS[t] = sc;
    stB[t] = be[t] - mean*sc;
  }
  __syncthreads();
}

// ---- DMA a linear bf16 weight block global->LDS (nchunks x 1KB) ----
__device__ __forceinline__ void dma_w(const ushortT* __restrict__ src, ushortT* dst,
                                      int nchunks, int w, int lane)
{
  const char* s = (const char*)src;
  char* d = (char*)dst;
  for (int i = w; i < nchunks; i += 16){
    __builtin_amdgcn_global_load_lds(
        (const __attribute__((address_space(1))) void*)(s + (size_t)i*1024 + (size_t)lane*16),
        (__attribute__((address_space(3))) void*)(d + (size_t)i*1024), 16, 0, 0);
  }
}

// ========== k_prep: transposes + packs + slot zeroing ==========
// blk 0..161  : proj -> bf16 projT[b][m][c] (LDS-tiled transpose)
// blk 162..177: orig -> f32 origT[b][n][20]
// blk 178..180: zero slots (12288 int64)
// blk 181..191: vertex -> vpk {x,y,z,v2}
// blk 192..212: W0 -> bf16 wpkg0 [128][168]
// blk 213..246: W1/W2 -> bf16 wpkg12 [2][128][136]
__global__ __launch_bounds__(1024) void k_prep(
    const float* __restrict__ proj, const float* __restrict__ orig,
    const float* __restrict__ vertex,
    const float* __restrict__ W0, const float* __restrict__ W1, const float* __restrict__ W2,
    ullT* __restrict__ slots, ushortT* __restrict__ wpkg0, ushortT* __restrict__ wpkg12,
    float* __restrict__ vpk, float* __restrict__ origT, ushortT* __restrict__ projT)
{
  __shared__ __align__(16) char lsb[40960];
  const int blk = blockIdx.x, t = threadIdx.x;

  if (blk < 162){
    ushortT (*tile)[132] = (ushortT(*)[132])lsb;
    int pb = blk / 81, mt = blk - pb*81, m0 = mt*128;
    {
      int c = t >> 3, ms = (t & 7) * 16;
      const float* src = proj + ((long)pb*128 + c)*N0V;
      #pragma unroll
      for (int j=0;j<16;j++){
        int m = m0 + ms + j;
        tile[c][ms+j] = f2bf((m < N0V) ? src[m] : 0.f);
      }
    }
    __syncthreads();
    {
      int ml = t >> 3, cs = (t & 7) * 16;
      int m = m0 + ml;
      if (m < N0V){
        ushortT* dst = projT + ((long)pb*N0V + m)*128 + cs;
        #pragma unroll
        for (int j=0;j<16;j++) dst[j] = tile[cs+j][ml];
      }
    }
  } else if (blk < 178){
    float (*tile)[516] = (float(*)[516])lsb;
    int u = blk - 162, pb = u >> 3, nt = u & 7, n0 = nt*512;
    for (int i = t; i < 19*512; i += 1024){
      int c = i >> 9, nn = i & 511;
      tile[c][nn] = orig[((long)pb*19 + c)*NPTS + n0 + nn];
    }
    __syncthreads();
    for (int i = t; i < 512*20; i += 1024){
      int nn = i / 20, c = i - nn*20;
      origT[((long)pb*NPTS + n0 + nn)*20 + c] = (c < 19) ? tile[c][nn] : 0.f;
    }
  } else if (blk < 181){
    int u0 = (blk-178)*4096 + t*4;     // 3 blocks x 1024 x 4 = 12288 int64
    slots[u0] = 0; slots[u0+1] = 0; slots[u0+2] = 0; slots[u0+3] = 0;
  } else if (blk < 192){
    int m = (blk-181)*1024 + t;
    if (m < N0V){
      float x = vertex[3*m], y = vertex[3*m+1], z = vertex[3*m+2];
      float v2 = fadd(fadd(fmul(x,x),fmul(y,y)),fmul(z,z));
      ((float4*)vpk)[m] = make_float4(x,y,z,v2);
    }
  } else if (blk < 213){
    int u = (blk-192)*1024 + t;
    if (u < 21504){
      int o = u/168, k = u - o*168;
      wpkg0[u] = f2bf((k < 147) ? W0[o*147 + k] : 0.f);
    }
  } else {
    int u = (blk-213)*1024 + t;
    if (u < 34816){
      int L = u / 17408, q = u - L*17408;
      int o = q/136, k = q - o*136;
      float v = 0.f;
      if (k < 128) v = L ? W2[o*128 + k] : W1[o*128 + k];
      wpkg12[u] = f2bf(v);
    }
  }
}

// ================= k_l0: DMA wt0 + scan(vpk) + gather(projT/origT) + L0 MFMA + y0 =============
__global__ __launch_bounds__(1024) void k_l0(
    const float* __restrict__ origT, const ushortT* __restrict__ projT,
    const float* __restrict__ vpk,
    const float* __restrict__ vertex, const int* __restrict__ nidx,
    const ushortT* __restrict__ wpkg0, const float* __restrict__ b0,
    ullT* __restrict__ slot0, ushortT* __restrict__ y0)
{
  __shared__ __align__(16) ushortT wt[128*168];
  __shared__ __align__(16) ushortT xa[32*168];

  const int t    = threadIdx.x;
  const int blk  = blockIdx.x;
  const int lane = t & 63;
  const int w    = t >> 6;
  const int b    = blk >> 7;
  const int n0   = (blk & 127) * 32;
  const int li   = lane & 15;
  const int hi   = lane >> 4;
  const int rt   = w >> 3;
  const int colg = (w & 7)*16 + li;

  dma_w(wpkg0, wt, 42, w, lane);     // 43008B async; drains at the syncthreads below

  // scan + gather: 2 rows per wave
  {
    float v0x=vertex[0], v0y=vertex[1], v0z=vertex[2];
    float r  = __fsqrt_rn(fadd(fadd(fmul(v0x,v0x),fmul(v0y,v0y)),fmul(v0z,v0z)));
    float rr = fmul(r,r);
    int j0 = nidx[0];
    float ax=vertex[3*j0], ay=vertex[3*j0+1], az=vertex[3*j0+2];
    float dx=fsub(v0x,ax), dy=fsub(v0y,ay), dz=fsub(v0z,az);
    float t2 = fadd(fadd(fmul(dx,dx),fmul(dy,dy)),fmul(dz,dz));
    const float4* vp4 = (const float4*)vpk;

    #pragma unroll
    for (int rr_i=0; rr_i<2; rr_i++){
      const int row = w*2 + rr_i;
      const int n = n0 + row;
      const float* rowO = origT + ((long)b*NPTS + n)*20;
      float x=rowO[0], y=rowO[1], z=rowO[2];
      float nrm = __fsqrt_rn(fadd(fadd(fmul(x,x),fmul(y,y)),fmul(z,z)));
      float s = __fdiv_rn(r,nrm);
      float px=fmul(x,s), py=fmul(y,s), pz=fmul(z,s);

      int first=0, has=0;
      for (int c0=0; c0<N0V; c0+=256){
        int m0=min(c0+lane,N0V-1), m1=min(c0+lane+64,N0V-1),
            m2=min(c0+lane+128,N0V-1), m3=min(c0+lane+192,N0V-1);
        float4 va = vp4[m0];
        float4 vb = vp4[m1];
        float4 vc = vp4[m2];
        float4 vd = vp4[m3];
        float d0=fadd(fadd(fmul(px,va.x),fmul(py,va.y)),fmul(pz,va.z));
        float d1=fadd(fadd(fmul(px,vb.x),fmul(py,vb.y)),fmul(pz,vb.z));
        float d2=fadd(fadd(fmul(px,vc.x),fmul(py,vc.y)),fmul(pz,vc.z));
        float d3=fadd(fadd(fmul(px,vd.x),fmul(py,vd.y)),fmul(pz,vd.z));
        bool h0 = (c0+lane    <N0V) && (fsub(fadd(rr,va.w),fmul(2.0f,d0)) <= t2);
        bool h1 = (c0+lane+64 <N0V) && (fsub(fadd(rr,vb.w),fmul(2.0f,d1)) <= t2);
        bool h2 = (c0+lane+128<N0V) && (fsub(fadd(rr,vc.w),fmul(2.0f,d2)) <= t2);
        bool h3 = (c0+lane+192<N0V) && (fsub(fadd(rr,vd.w),fmul(2.0f,d3)) <= t2);
        unsigned long long bal;
        if ((bal=__ballot(h0))){ first=c0     +__builtin_ctzll(bal); has=1; break; }
        if ((bal=__ballot(h1))){ first=c0+ 64+__builtin_ctzll(bal); has=1; break; }
        if ((bal=__ballot(h2))){ first=c0+128+__builtin_ctzll(bal); has=1; break; }
        if ((bal=__ballot(h3))){ first=c0+192+__builtin_ctzll(bal); has=1; break; }
      }

      ushortT* rowp = xa + row*168;
      const ushortT* pr = projT + ((long)b*N0V + first)*128;
      #pragma unroll
      for (int k=0;k<3;k++){
        int idx = lane + k*64;
        if (idx < 168){
          ushortT v;
          if (idx < 19)        v = f2bf(rowO[idx]);
          else if (idx < 147)  v = has ? pr[idx-19] : (ushortT)0;
          else                 v = 0;
          rowp[idx] = v;
        }
      }
    }
  }
  __syncthreads();   // xa ready AND wt0 DMA drained

  f32x4 acc;
  tile_mm<5>(xa, wt, 168, li, hi, rt, colg, acc);
  float bo = b0[colg];
  #pragma unroll
  for (int r=0;r<4;r++) acc[r] += bo;
  tile_partials(acc, slot0, blk, lane, colg);
  #pragma unroll
  for (int r=0;r<4;r++)
    y0[(long)(b*4096 + n0 + rt*16 + hi*4 + r)*128 + colg] = f2bf(acc[r]);
}

// ================= k_lmid: DMA wt + stats(prev slots) + affine + MFMA + partials + y out ======
__global__ __launch_bounds__(1024) void k_lmid(
    const ushortT* __restrict__ yin, const ullT* __restrict__ slotPrev,
    const float* __restrict__ g, const float* __restrict__ be,
    const ushortT* __restrict__ wpk, const float* __restrict__ bias,
    ullT* __restrict__ slotCur, ushortT* __restrict__ yout)
{
  __shared__ __align__(16) ushortT wt[128*136];
  __shared__ __align__(16) ushortT xa[32*168];
  __shared__ float red2[256];
  __shared__ float stS[128];
  __shared__ float stB[128];

  const int t    = threadIdx.x;
  const int blk  = blockIdx.x;
  const int lane = t & 63;
  const int w    = t >> 6;
  const int n0   = blk * 32;
  const int li   = lane & 15;
  const int hi   = lane >> 4;
  const int rt   = w >> 3;
  const int colg = (w & 7)*16 + li;

  dma_w(wpk, wt, 34, w, lane);

  for (int u = t; u < 1280; u += 1024){
    int row = u/40, c = 128 + (u - row*40);
    xa[row*168 + c] = 0;
  }
  slot_stats(slotPrev, g, be, red2, stS, stB, t);

  if (t < 512){
    int row = t >> 4, c0 = (t & 15) * 8;
    short8 yv = *(const short8*)(yin + (long)(n0+row)*128 + c0);
    short8 xv;
    #pragma unroll
    for (int j=0;j<8;j++){
      float f = bf2f((ushortT)yv[j]);
      f = fmaxf(fmaf(f, stS[c0+j], stB[c0+j]), 0.f);
      xv[j] = (short)f2bf(f);
    }
    *(short8*)(xa + row*168 + c0) = xv;
  }
  __syncthreads();

  f32x4 acc;
  tile_mm<4>(xa, wt, 136, li, hi, rt, colg, acc);
  float bo = bias[colg];
  #pragma unroll
  for (int r=0;r<4;r++) acc[r] += bo;
  tile_partials(acc, slotCur, blk, lane, colg);
  #pragma unroll
  for (int r=0;r<4;r++)
    yout[(long)(n0 + rt*16 + hi*4 + r)*128 + colg] = f2bf(acc[r]);
}

// ================= k_out: stats(L2 slots) + affine/relu + transpose + store ==================
__global__ __launch_bounds__(1024) void k_out(
    const ushortT* __restrict__ yin, const ullT* __restrict__ slotPrev,
    const float* __restrict__ g, const float* __restrict__ be,
    float* __restrict__ out)
{
  __shared__ float ft[32*132];
  __shared__ float red2[256];
  __shared__ float stS[128];
  __shared__ float stB[128];

  const int t   = threadIdx.x;
  const int blk = blockIdx.x;
  const int b   = blk >> 7;
  const int n0  = (blk & 127) * 32;

  slot_stats(slotPrev, g, be, red2, stS, stB, t);

  if (t < 512){
    int row = t >> 4, c0 = (t & 15) * 8;
    short8 yv = *(const short8*)(yin + (long)(b*4096 + n0 + row)*128 + c0);
    #pragma unroll
    for (int j=0;j<8;j++)
      ft[row*132 + c0 + j] = fmaxf(fmaf(bf2f((ushortT)yv[j]), stS[c0+j], stB[c0+j]), 0.f);
  }
  __syncthreads();

  float* ob = out + (long)b*128*NPTS + n0;
  {
    int oo = t >> 3, jj = (t & 7) * 4;
    float4 v;
    v.x = ft[(jj  )*132 + oo];
    v.y = ft[(jj+1)*132 + oo];
    v.z = ft[(jj+2)*132 + oo];
    v.w = ft[(jj+3)*132 + oo];
    *(float4*)(ob + (long)oo*NPTS + jj) = v;
  }
}

extern "C" void kernel_launch(void* const* d_in, const int* in_sizes, int n_in,
                              void* d_out, int out_size, void* d_ws, size_t ws_size,
                              hipStream_t stream)
{
  const float* orig   = (const float*)d_in[0];
  const float* proj   = (const float*)d_in[1];
  const float* vertex = (const float*)d_in[2];
  const int*   nidx   = (const int*)d_in[3];
  const float* W0 = (const float*)d_in[4];
  const float* b0 = (const float*)d_in[5];
  const float* g0 = (const float*)d_in[6];
  const float* be0= (const float*)d_in[7];
  const float* W1 = (const float*)d_in[8];
  const float* b1 = (const float*)d_in[9];
  const float* g1 = (const float*)d_in[10];
  const float* be1= (const float*)d_in[11];
  const float* W2 = (const float*)d_in[12];
  const float* b2 = (const float*)d_in[13];
  const float* g2 = (const float*)d_in[14];
  const float* be2= (const float*)d_in[15];
  float* out = (float*)d_out;

  float*   ws     = (float*)d_ws;
  ullT*    slots  = (ullT*)ws;                   // 3 x 16 x 256 int64 = 12288 ll = 24576 fl
  ullT*    slot0  = slots;
  ullT*    slot1  = slots + 4096;
  ullT*    slot2  = slots + 8192;
  ushortT* wpkg0  = (ushortT*)(ws + 24576);      // 21504 ush = 10752 fl
  ushortT* wpkg12 = (ushortT*)(ws + 35328);      // 34816 ush = 17408 fl
  float*   vpk    = ws + 52736;                  // 10242 float4 = 40968 fl
  float*   origT  = ws + 93704;                  // 2*4096*20 = 163840 fl
  ushortT* projT  = (ushortT*)(ws + 257544);     // 2*10242*128 ush = 1310976 fl
  ushortT* yA     = (ushortT*)(ws + 1568520);    // 8192*128 ush = 524288 fl
  ushortT* yB     = yA + 8192*128;               // ends ~10.5MB

  k_prep<<<247, 1024, 0, stream>>>(proj, orig, vertex, W0, W1, W2,
                                   slots, wpkg0, wpkg12, vpk, origT, projT);
  k_l0  <<<256, 1024, 0, stream>>>(origT, projT, vpk, vertex, nidx, wpkg0, b0, slot0, yA);
  k_lmid<<<256, 1024, 0, stream>>>(yA, slot0, g0, be0, wpkg12,         b1, slot1, yB);
  k_lmid<<<256, 1024, 0, stream>>>(yB, slot1, g1, be1, wpkg12 + 17408, b2, slot2, yA);
  k_out <<<256, 1024, 0, stream>>>(yA, slot2, g2, be2, out);
}

// Round 21
// 30.943 us; speedup vs baseline: 1.1395x; 1.1395x over previous
//
#include <hip/hip_runtime.h>

#define NPTS 4096
#define N0V  10242
#define EPSV 1e-5f
#define SLOTS 16
#define FXS 16777216.0   // 2^24 fixed-point scale

typedef unsigned short ushortT;
typedef unsigned long long ullT;
typedef __attribute__((ext_vector_type(8))) short short8;
typedef __attribute__((ext_vector_type(4))) float f32x4;

__device__ __forceinline__ float fmul(float a,float b){return __fmul_rn(a,b);}
__device__ __forceinline__ float fadd(float a,float b){return __fadd_rn(a,b);}
__device__ __forceinline__ float fsub(float a,float b){return __fsub_rn(a,b);}

__device__ __forceinline__ ushortT f2bf(float x){
  unsigned u = __float_as_uint(x);
  u = (u + 0x7fffu + ((u>>16)&1u)) >> 16;
  return (ushortT)u;
}
__device__ __forceinline__ float bf2f(ushortT u){
  return __uint_as_float(((unsigned)u) << 16);
}

// ---- per-wave 16x16 MFMA tile ----
template<int NS>
__device__ __forceinline__ void tile_mm(const ushortT* xa, const ushortT* wt, int wstr,
    int li, int hi, int rt, int colg, f32x4& acc)
{
  acc = (f32x4){0.f,0.f,0.f,0.f};
  const ushortT* wbp = wt + colg*wstr + hi*8;
  const ushortT* xap = xa + (rt*16 + li)*168 + hi*8;
  #pragma unroll
  for (int s=0;s<NS;s++){
    short8 bb = *(const short8*)(wbp + s*32);
    short8 a0 = *(const short8*)(xap + s*32);
    acc = __builtin_amdgcn_mfma_f32_16x16x32_bf16(a0, bb, acc, 0,0,0);
  }
}

// ---- per-wave partials -> DETERMINISTIC fixed-point int64 atomicAdd into 16 slots ----
// (float atomicAdd ordering is run-to-run nondeterministic -> R19 replay-divergence;
//  integer adds are associative/commutative -> bitwise-reproducible stats)
__device__ __forceinline__ void tile_partials(const f32x4& acc, ullT* __restrict__ slotL,
                                              int blk, int lane, int colg)
{
  float s1=0.f, s2=0.f;
  #pragma unroll
  for (int r=0;r<4;r++){ s1 += acc[r]; s2 = fmaf(acc[r],acc[r],s2); }
  s1 += __shfl_xor(s1,16); s1 += __shfl_xor(s1,32);
  s2 += __shfl_xor(s2,16); s2 += __shfl_xor(s2,32);
  if (lane < 16){
    ullT* sl = slotL + (blk & (SLOTS-1))*256;
    long long q1 = __double2ll_rn((double)s1 * FXS);
    long long q2 = __double2ll_rn((double)s2 * FXS);
    atomicAdd(&sl[colg],       (ullT)q1);
    atomicAdd(&sl[128 + colg], (ullT)q2);
  }
}

// ---- stats from previous kernel's slots: plain int64 loads (inter-dispatch barrier = sync) ----
__device__ __forceinline__ void slot_stats(const ullT* __restrict__ slotL,
    const float* __restrict__ g, const float* __restrict__ be,
    float* red2, float* stS, float* stB, int t)
{
  if (t < 256){
    long long v = 0;
    #pragma unroll
    for (int s=0;s<SLOTS;s++) v += (long long)slotL[s*256 + t];
    red2[t] = (float)((double)v * (1.0/FXS));
  }
  __syncthreads();
  if (t < 128){
    float S = red2[t], Q = red2[128 + t];
    float mean = S * (1.0f/8192.0f);
    float var  = Q * (1.0f/8192.0f) - mean*mean;
    float inv  = 1.0f / __fsqrt_rn(var + EPSV);
    float sc = g[t]*inv;
    stS[t] = sc;
    stB[t] = be[t] - mean*sc;
  }
  __syncthreads();
}

// ---- DMA a linear bf16 weight block global->LDS (nchunks x 1KB) ----
__device__ __forceinline__ void dma_w(const ushortT* __restrict__ src, ushortT* dst,
                                      int nchunks, int w, int lane)
{
  const char* s = (const char*)src;
  char* d = (char*)dst;
  for (int i = w; i < nchunks; i += 16){
    __builtin_amdgcn_global_load_lds(
        (const __attribute__((address_space(1))) void*)(s + (size_t)i*1024 + (size_t)lane*16),
        (__attribute__((address_space(3))) void*)(d + (size_t)i*1024), 16, 0, 0);
  }
}

// ================= k_l0: scan + gather + pack wt0 + L0 MFMA + partials + y0(bf16)
//                   side jobs: zero slot1/slot2; pack W1/W2 -> global bf16 wpkg =================
__global__ __launch_bounds__(1024) void k_l0(
    const float* __restrict__ orig, const float* __restrict__ proj,
    const float* __restrict__ vertex, const int* __restrict__ nidx,
    const float* __restrict__ W0, const float* __restrict__ b0,
    const float* __restrict__ W1, const float* __restrict__ W2,
    ullT* __restrict__ slot0, ullT* __restrict__ slotZ,
    ushortT* __restrict__ wpkg, ushortT* __restrict__ y0)
{
  __shared__ __align__(16) ushortT wt[128*168];
  __shared__ __align__(16) ushortT xa[32*168];

  const int t    = threadIdx.x;
  const int blk  = blockIdx.x;
  const int lane = t & 63;
  const int w    = t >> 6;
  const int b    = blk >> 7;
  const int n0   = (blk & 127) * 32;
  const int li   = lane & 15;
  const int hi   = lane >> 4;
  const int rt   = w >> 3;
  const int colg = (w & 7)*16 + li;

  // zero slot1+slot2 (8 blocks x 1024 ullT = 8192 int64)
  if (blk < 8) slotZ[blk*1024 + t] = 0ULL;

  // pack W1/W2 -> global bf16 [2][128][136] (136 els per block; 256*136 = 34816)
  if (t < 136){
    int u = blk*136 + t;
    int L = u / 17408, q = u - L*17408;
    int o = q / 136, k = q - o*136;
    float v = 0.f;
    if (k < 128) v = (L == 0) ? W1[o*128 + k] : W2[o*128 + k];
    wpkg[u] = f2bf(v);
  }

  // pack wt0 f32->bf16 into LDS
  for (int u = t; u < 21504; u += 1024){
    int o = u/168, k = u - o*168;
    wt[u] = f2bf((k < 147) ? W0[o*147 + k] : 0.f);
  }

  // scan + gather: 2 rows per wave
  {
    float v0x=vertex[0], v0y=vertex[1], v0z=vertex[2];
    float r  = __fsqrt_rn(fadd(fadd(fmul(v0x,v0x),fmul(v0y,v0y)),fmul(v0z,v0z)));
    float rr = fmul(r,r);
    int j0 = nidx[0];
    float ax=vertex[3*j0], ay=vertex[3*j0+1], az=vertex[3*j0+2];
    float dx=fsub(v0x,ax), dy=fsub(v0y,ay), dz=fsub(v0z,az);
    float t2 = fadd(fadd(fmul(dx,dx),fmul(dy,dy)),fmul(dz,dz));

    #pragma unroll
    for (int rr_i=0; rr_i<2; rr_i++){
      const int row = w*2 + rr_i;
      const int n = n0 + row;
      const float* ob = orig + (b*19)*NPTS + n;
      float x=ob[0], y=ob[NPTS], z=ob[2*NPTS];
      float nrm = __fsqrt_rn(fadd(fadd(fmul(x,x),fmul(y,y)),fmul(z,z)));
      float s = __fdiv_rn(r,nrm);
      float px=fmul(x,s), py=fmul(y,s), pz=fmul(z,s);

      int first=0, has=0;
      for (int c0=0; c0<N0V; c0+=256){
        int m0=min(c0+lane,N0V-1), m1=min(c0+lane+64,N0V-1),
            m2=min(c0+lane+128,N0V-1), m3=min(c0+lane+192,N0V-1);
        float a0x=vertex[3*m0],a0y=vertex[3*m0+1],a0z=vertex[3*m0+2];
        float a1x=vertex[3*m1],a1y=vertex[3*m1+1],a1z=vertex[3*m1+2];
        float a2x=vertex[3*m2],a2y=vertex[3*m2+1],a2z=vertex[3*m2+2];
        float a3x=vertex[3*m3],a3y=vertex[3*m3+1],a3z=vertex[3*m3+2];
        float v20=fadd(fadd(fmul(a0x,a0x),fmul(a0y,a0y)),fmul(a0z,a0z));
        float v21=fadd(fadd(fmul(a1x,a1x),fmul(a1y,a1y)),fmul(a1z,a1z));
        float v22=fadd(fadd(fmul(a2x,a2x),fmul(a2y,a2y)),fmul(a2z,a2z));
        float v23=fadd(fadd(fmul(a3x,a3x),fmul(a3y,a3y)),fmul(a3z,a3z));
        float d0=fadd(fadd(fmul(px,a0x),fmul(py,a0y)),fmul(pz,a0z));
        float d1=fadd(fadd(fmul(px,a1x),fmul(py,a1y)),fmul(pz,a1z));
        float d2=fadd(fadd(fmul(px,a2x),fmul(py,a2y)),fmul(pz,a2z));
        float d3=fadd(fadd(fmul(px,a3x),fmul(py,a3y)),fmul(pz,a3z));
        bool h0 = (c0+lane    <N0V) && (fsub(fadd(rr,v20),fmul(2.0f,d0)) <= t2);
        bool h1 = (c0+lane+64 <N0V) && (fsub(fadd(rr,v21),fmul(2.0f,d1)) <= t2);
        bool h2 = (c0+lane+128<N0V) && (fsub(fadd(rr,v22),fmul(2.0f,d2)) <= t2);
        bool h3 = (c0+lane+192<N0V) && (fsub(fadd(rr,v23),fmul(2.0f,d3)) <= t2);
        unsigned long long bal;
        if ((bal=__ballot(h0))){ first=c0     +__builtin_ctzll(bal); has=1; break; }
        if ((bal=__ballot(h1))){ first=c0+ 64+__builtin_ctzll(bal); has=1; break; }
        if ((bal=__ballot(h2))){ first=c0+128+__builtin_ctzll(bal); has=1; break; }
        if ((bal=__ballot(h3))){ first=c0+192+__builtin_ctzll(bal); has=1; break; }
      }

      ushortT* rowp = xa + row*168;
      const float* pb = proj + (long)b*128*N0V;
      #pragma unroll
      for (int k=0;k<3;k++){
        int idx = lane + k*64;
        if (idx < 168){
          float v;
          if (idx < 19)        v = orig[(b*19+idx)*NPTS + n];
          else if (idx < 147)  v = has ? pb[(long)(idx-19)*N0V + first] : 0.0f;
          else                 v = 0.0f;
          rowp[idx] = f2bf(v);
        }
      }
    }
  }
  __syncthreads();

  f32x4 acc;
  tile_mm<5>(xa, wt, 168, li, hi, rt, colg, acc);
  float bo = b0[colg];
  #pragma unroll
  for (int r=0;r<4;r++) acc[r] += bo;
  tile_partials(acc, slot0, blk, lane, colg);
  #pragma unroll
  for (int r=0;r<4;r++)
    y0[(long)(b*4096 + n0 + rt*16 + hi*4 + r)*128 + colg] = f2bf(acc[r]);
}

// ================= k_lmid: DMA wt + stats(prev slots) + affine + MFMA + partials + y out ======
__global__ __launch_bounds__(1024) void k_lmid(
    const ushortT* __restrict__ yin, const ullT* __restrict__ slotPrev,
    const float* __restrict__ g, const float* __restrict__ be,
    const ushortT* __restrict__ wpk, const float* __restrict__ bias,
    ullT* __restrict__ slotCur, ushortT* __restrict__ yout)
{
  __shared__ __align__(16) ushortT wt[128*136];
  __shared__ __align__(16) ushortT xa[32*168];
  __shared__ float red2[256];
  __shared__ float stS[128];
  __shared__ float stB[128];

  const int t    = threadIdx.x;
  const int blk  = blockIdx.x;
  const int lane = t & 63;
  const int w    = t >> 6;
  const int n0   = blk * 32;
  const int li   = lane & 15;
  const int hi   = lane >> 4;
  const int rt   = w >> 3;
  const int colg = (w & 7)*16 + li;

  dma_w(wpk, wt, 34, w, lane);

  for (int u = t; u < 1280; u += 1024){
    int row = u/40, c = 128 + (u - row*40);
    xa[row*168 + c] = 0;
  }
  slot_stats(slotPrev, g, be, red2, stS, stB, t);

  if (t < 512){
    int row = t >> 4, c0 = (t & 15) * 8;
    short8 yv = *(const short8*)(yin + (long)(n0+row)*128 + c0);
    short8 xv;
    #pragma unroll
    for (int j=0;j<8;j++){
      float f = bf2f((ushortT)yv[j]);
      f = fmaxf(fmaf(f, stS[c0+j], stB[c0+j]), 0.f);
      xv[j] = (short)f2bf(f);
    }
    *(short8*)(xa + row*168 + c0) = xv;
  }
  __syncthreads();

  f32x4 acc;
  tile_mm<4>(xa, wt, 136, li, hi, rt, colg, acc);
  float bo = bias[colg];
  #pragma unroll
  for (int r=0;r<4;r++) acc[r] += bo;
  tile_partials(acc, slotCur, blk, lane, colg);
  #pragma unroll
  for (int r=0;r<4;r++)
    yout[(long)(n0 + rt*16 + hi*4 + r)*128 + colg] = f2bf(acc[r]);
}

// ================= k_out: stats(L2 slots) + affine/relu + transpose + store ==================
__global__ __launch_bounds__(1024) void k_out(
    const ushortT* __restrict__ yin, const ullT* __restrict__ slotPrev,
    const float* __restrict__ g, const float* __restrict__ be,
    float* __restrict__ out)
{
  __shared__ float ft[32*132];
  __shared__ float red2[256];
  __shared__ float stS[128];
  __shared__ float stB[128];

  const int t   = threadIdx.x;
  const int blk = blockIdx.x;
  const int b   = blk >> 7;
  const int n0  = (blk & 127) * 32;

  slot_stats(slotPrev, g, be, red2, stS, stB, t);

  if (t < 512){
    int row = t >> 4, c0 = (t & 15) * 8;
    short8 yv = *(const short8*)(yin + (long)(b*4096 + n0 + row)*128 + c0);
    #pragma unroll
    for (int j=0;j<8;j++)
      ft[row*132 + c0 + j] = fmaxf(fmaf(bf2f((ushortT)yv[j]), stS[c0+j], stB[c0+j]), 0.f);
  }
  __syncthreads();

  float* ob = out + (long)b*128*NPTS + n0;
  {
    int oo = t >> 3, jj = (t & 7) * 4;
    float4 v;
    v.x = ft[(jj  )*132 + oo];
    v.y = ft[(jj+1)*132 + oo];
    v.z = ft[(jj+2)*132 + oo];
    v.w = ft[(jj+3)*132 + oo];
    *(float4*)(ob + (long)oo*NPTS + jj) = v;
  }
}

extern "C" void kernel_launch(void* const* d_in, const int* in_sizes, int n_in,
                              void* d_out, int out_size, void* d_ws, size_t ws_size,
                              hipStream_t stream)
{
  const float* orig   = (const float*)d_in[0];
  const float* proj   = (const float*)d_in[1];
  const float* vertex = (const float*)d_in[2];
  const int*   nidx   = (const int*)d_in[3];
  const float* W0 = (const float*)d_in[4];
  const float* b0 = (const float*)d_in[5];
  const float* g0 = (const float*)d_in[6];
  const float* be0= (const float*)d_in[7];
  const float* W1 = (const float*)d_in[8];
  const float* b1 = (const float*)d_in[9];
  const float* g1 = (const float*)d_in[10];
  const float* be1= (const float*)d_in[11];
  const float* W2 = (const float*)d_in[12];
  const float* b2 = (const float*)d_in[13];
  const float* g2 = (const float*)d_in[14];
  const float* be2= (const float*)d_in[15];
  float* out = (float*)d_out;

  float*   ws    = (float*)d_ws;
  ullT*    slots = (ullT*)ws;                  // 3 x 16 x 256 int64 (24576 floats)
  ullT*    slot0 = slots;
  ullT*    slot1 = slots + 4096;
  ullT*    slot2 = slots + 8192;
  ushortT* wpkg  = (ushortT*)(ws + 24576);     // 34816 ush = 17408 fl
  ushortT* yA    = (ushortT*)(ws + 41984);     // 8192*128 ush = 524288 fl
  ushortT* yB    = yA + 8192*128;

  hipMemsetAsync(d_ws, 0, 4096*sizeof(ullT), stream);   // slot0; slot1/2 zeroed by k_l0

  k_l0  <<<256, 1024, 0, stream>>>(orig, proj, vertex, nidx, W0, b0, W1, W2,
                                   slot0, slot1, wpkg, yA);
  k_lmid<<<256, 1024, 0, stream>>>(yA, slot0, g0, be0, wpkg,         b1, slot1, yB);
  k_lmid<<<256, 1024, 0, stream>>>(yB, slot1, g1, be1, wpkg + 17408, b2, slot2, yA);
  k_out <<<256, 1024, 0, stream>>>(yA, slot2, g2, be2, out);
}